// Round 8
// baseline (103.532 us; speedup 1.0000x reference)
//
#include <hip/hip_runtime.h>

#define BN_EPS 1e-5f

// ws layout (floats) — every region fully written each launch (no memset needed
// in the main path; deterministic, no float atomics)
#define OFF_PBN     0          // [256 blk][32]  conv BN partials (sum k<16, sq 16+k)
#define OFF_PSR     8192       // [512 blk][32]  SR/SRR partials
#define OFF_PSX     24576      // [b*256+r][256] SX partials (r = s*2+ih)
#define OFF_PSXX    286720     // [b*256+r][256] SXX partials
#define OFF_CROSSR  548864     // [4 sg][4 b][16 k][256 c]
#define OFF_SXF     614400     // [4 b][4 sg][2 {sx,sxx}][256 c] = 8192
#define OFF_CW      622592     // [b][k][4096] = 262144
#define OFF_PCX     884736     // [(b*256+r)][16][256] = 4194304
#define WS_NEED     ((size_t)(OFF_PCX + 4194304) * sizeof(float))

#define CONV_FMA(W, K0, XV)                              \
    acc[K0][0] = fmaf(W, XV.x, acc[K0][0]);              \
    acc[K0][1] = fmaf(W, XV.y, acc[K0][1]);              \
    acc[K0][2] = fmaf(W, XV.z, acc[K0][2]);              \
    acc[K0][3] = fmaf(W, XV.w, acc[K0][3]);

#define FMA16(v, rp)                                     \
    {                                                    \
        const float4* rq_ = (const float4*)(rp);         \
        float4 r0_ = rq_[0], r1_ = rq_[1];               \
        float4 r2_ = rq_[2], r3_ = rq_[3];               \
        acc[0]  = fmaf(v, r0_.x, acc[0]);                \
        acc[1]  = fmaf(v, r0_.y, acc[1]);                \
        acc[2]  = fmaf(v, r0_.z, acc[2]);                \
        acc[3]  = fmaf(v, r0_.w, acc[3]);                \
        acc[4]  = fmaf(v, r1_.x, acc[4]);                \
        acc[5]  = fmaf(v, r1_.y, acc[5]);                \
        acc[6]  = fmaf(v, r1_.z, acc[6]);                \
        acc[7]  = fmaf(v, r1_.w, acc[7]);                \
        acc[8]  = fmaf(v, r2_.x, acc[8]);                \
        acc[9]  = fmaf(v, r2_.y, acc[9]);                \
        acc[10] = fmaf(v, r2_.z, acc[10]);               \
        acc[11] = fmaf(v, r2_.w, acc[11]);               \
        acc[12] = fmaf(v, r3_.x, acc[12]);               \
        acc[13] = fmaf(v, r3_.y, acc[13]);               \
        acc[14] = fmaf(v, r3_.z, acc[14]);               \
        acc[15] = fmaf(v, r3_.w, acc[15]);               \
    }

// ---------------- Kernel 1: 1x1 conv + BN partials ----------------
// grid 256 = 4(b) x 64(ich of 64 i); block 512: il = t&15 (float4 -> 64 i),
// cp = t>>4 (8 channels each). Per wave: il = lane bits 0-3, cp low 2 bits =
// lane bits 4-5 -> butterfly over those; wave w owns channels [w*32, w*32+32).
__global__ __launch_bounds__(512, 2) void k_conv(const float* __restrict__ x,
                                                 const float* __restrict__ wq,
                                                 float* __restrict__ cw,
                                                 float* __restrict__ pbn) {
    __shared__ float wlT[4224];       // wlT[c*16 + (c>>3)*4 + k]
    __shared__ float wred[8 * 1088];  // [wave][il*68 + k*4 + e]  (68 = bank skew)
    int bid = blockIdx.x;
    int b   = bid >> 6;
    int ich = bid & 63;
    int t   = threadIdx.x;
    int il  = t & 15;
    int cp  = t >> 4;                 // 0..31
    int wv  = t >> 6;

    for (int m = t; m < 4096; m += 512) {
        int k = m >> 8, c = m & 255;
        wlT[c * 16 + (c >> 3) * 4 + k] = wq[m];
    }
    __syncthreads();

    // preload all 8 x float4s (independent, deep MLP)
    float4 xv[8];
    const float* xp = x + (size_t)(b * 256 + cp * 8) * 4096 + ich * 64 + il * 4;
    #pragma unroll
    for (int cc = 0; cc < 8; ++cc) xv[cc] = *(const float4*)(xp + (size_t)cc * 4096);

    float acc[16][4];
    #pragma unroll
    for (int k = 0; k < 16; ++k) {
        #pragma unroll
        for (int e = 0; e < 4; ++e) acc[k][e] = 0.f;
    }

    #pragma unroll
    for (int cc = 0; cc < 8; ++cc) {
        int c = cp * 8 + cc;
        const float4* wr = (const float4*)&wlT[c * 16 + (c >> 3) * 4];
        float4 w0 = wr[0], w1 = wr[1], w2 = wr[2], w3 = wr[3];
        CONV_FMA(w0.x, 0,  xv[cc]) CONV_FMA(w0.y, 1,  xv[cc])
        CONV_FMA(w0.z, 2,  xv[cc]) CONV_FMA(w0.w, 3,  xv[cc])
        CONV_FMA(w1.x, 4,  xv[cc]) CONV_FMA(w1.y, 5,  xv[cc])
        CONV_FMA(w1.z, 6,  xv[cc]) CONV_FMA(w1.w, 7,  xv[cc])
        CONV_FMA(w2.x, 8,  xv[cc]) CONV_FMA(w2.y, 9,  xv[cc])
        CONV_FMA(w2.z, 10, xv[cc]) CONV_FMA(w2.w, 11, xv[cc])
        CONV_FMA(w3.x, 12, xv[cc]) CONV_FMA(w3.y, 13, xv[cc])
        CONV_FMA(w3.z, 14, xv[cc]) CONV_FMA(w3.w, 15, xv[cc])
    }

    // reduce-scatter over the wave's 4 cp (lane bits 4,5); static reg indexing.
    float r8[8][4];
    #pragma unroll
    for (int r = 0; r < 8; ++r) {
        #pragma unroll
        for (int e = 0; e < 4; ++e) {
            float lo = acc[r][e]     + __shfl_xor(acc[r][e], 16);
            float hi = acc[r + 8][e] + __shfl_xor(acc[r + 8][e], 16);
            r8[r][e] = (cp & 1) ? hi : lo;
        }
    }
    float r4[4][4];
    #pragma unroll
    for (int r = 0; r < 4; ++r) {
        #pragma unroll
        for (int e = 0; e < 4; ++e) {
            float lo = r8[r][e]     + __shfl_xor(r8[r][e], 32);
            float hi = r8[r + 4][e] + __shfl_xor(r8[r + 4][e], 32);
            r4[r][e] = (cp & 2) ? hi : lo;
        }
    }
    int ko = (cp & 1) * 8 + ((cp >> 1) & 1) * 4;   // k-base; lane owns k = ko..ko+3
    #pragma unroll
    for (int j = 0; j < 4; ++j) {
        float4 v;
        v.x = r4[j][0]; v.y = r4[j][1]; v.z = r4[j][2]; v.w = r4[j][3];
        *(float4*)&wred[wv * 1088 + il * 68 + (ko + j) * 4] = v;
    }
    __syncthreads();

    // combine 8 waves; store cw; BN partials. threads 0-255: (k = t>>4, il = t&15)
    if (t < 256) {
        int k = t >> 4, ilo = t & 15;
        float4 s;
        s.x = 0.f; s.y = 0.f; s.z = 0.f; s.w = 0.f;
        #pragma unroll
        for (int w8 = 0; w8 < 8; ++w8) {
            float4 v = *(const float4*)&wred[w8 * 1088 + ilo * 68 + k * 4];
            s.x += v.x; s.y += v.y; s.z += v.z; s.w += v.w;
        }
        *(float4*)(cw + (size_t)b * 65536 + (size_t)k * 4096 + ich * 64 + ilo * 4) = s;

        float s1 = s.x + s.y + s.z + s.w;
        float s2 = s.x * s.x + s.y * s.y + s.z * s.z + s.w * s.w;
        #pragma unroll
        for (int m = 1; m <= 8; m <<= 1) {
            s1 += __shfl_xor(s1, m);
            s2 += __shfl_xor(s2, m);
        }
        if (ilo == 0) {
            pbn[bid * 32 + k]      = s1;
            pbn[bid * 32 + 16 + k] = s2;
        }
    }
}

// ---------------- Kernel 2: BN apply + Sr/Srr + Cross/Sx/Sxx partials ----------
// grid 512 = 4(b) x 128(slab of 32 i); block 512: c = t&255, ih = t>>8 (ii-half).
template <bool PCX>
__global__ __launch_bounds__(512, 2) void k_main(const float* __restrict__ x,
                                                 const float* __restrict__ gamma,
                                                 const float* __restrict__ beta,
                                                 float* __restrict__ ws,
                                                 float* __restrict__ pcx) {
    __shared__ float xl[8192];        // xl[i*256 + (c^i)] : XOR swizzle
    __shared__ float rl[512];
    __shared__ float red1[256], red2[256];
    __shared__ float bnred[256];
    int bid = blockIdx.x;
    int b   = bid >> 7;
    int s   = bid & 127;
    int kp  = s >> 3;                 // flat slab of 512 inside one orig channel
    int t   = threadIdx.x;
    int c   = t & 255;
    int ih  = t >> 8;

    // stage x slab (256 c x 32 i): coalesced float4 reads, swizzled LDS writes
    #pragma unroll
    for (int j = 0; j < 4; ++j) {
        int F  = j * 512 + t;         // 2048 float4s
        int cc = F >> 3, i4 = F & 7;
        const float* pa = x + (size_t)(b * 256 + cc) * 4096 + s * 32 + i4 * 4;
        float4 v = *(const float4*)pa;
        int ib = i4 * 4;
        xl[(ib + 0) * 256 + (cc ^ (ib + 0))] = v.x;
        xl[(ib + 1) * 256 + (cc ^ (ib + 1))] = v.y;
        xl[(ib + 2) * 256 + (cc ^ (ib + 2))] = v.z;
        xl[(ib + 3) * 256 + (cc ^ (ib + 3))] = v.w;
    }

    // BN stats: deterministic reduce of k_conv's 256x32 partials
    if (t < 256) {
        int col = t & 31, row0 = t >> 5;
        float p = 0.f;
        for (int m = row0; m < 256; m += 8) p += ws[OFF_PBN + m * 32 + col];
        bnred[t] = p;
    }
    __syncthreads();
    float s1 = 0.f, s2 = 0.f;
    #pragma unroll
    for (int j = 0; j < 8; ++j) {
        s1 += bnred[j * 32 + kp];
        s2 += bnred[j * 32 + 16 + kp];
    }
    float mean = s1 * (1.f / 16384.f);
    float var  = s2 * (1.f / 16384.f) - mean * mean;
    float aa   = gamma[kp] * rsqrtf(var + BN_EPS);
    float bb   = beta[kp] - mean * aa;

    // r values: BN+ReLU of this slab's 512 flat cw entries; k2 = flat & 15
    {
        float v = ws[OFF_CW + (size_t)b * 65536 + (size_t)kp * 4096
                     + (size_t)(s & 7) * 512 + t];
        rl[t] = fmaxf(fmaf(v, aa, bb), 0.f);
    }
    __syncthreads();

    if (t < 256) {
        float v1 = rl[t], v2 = rl[t + 256];
        red1[t] = v1 + v2;
        red2[t] = v1 * v1 + v2 * v2;
    }
    __syncthreads();
    if (t < 16) {
        float a1 = 0.f, a2 = 0.f;
        for (int m = t; m < 256; m += 16) { a1 += red1[m]; a2 += red2[m]; }
        ws[OFF_PSR + bid * 32 + t]      = a1;
        ws[OFF_PSR + bid * 32 + 16 + t] = a2;
    }

    // Cross partial: thread = (c, ih); 16 i from swizzled LDS; rl broadcast b128
    float acc[16];
    #pragma unroll
    for (int k = 0; k < 16; ++k) acc[k] = 0.f;
    float xs = 0.f, xs2 = 0.f;
    #pragma unroll
    for (int q = 0; q < 16; ++q) {
        int ii = ih * 16 + q;
        float xvv = xl[ii * 256 + (c ^ ii)];
        xs += xvv; xs2 += xvv * xvv;
        FMA16(xvv, rl + ii * 16);
    }

    ws[OFF_PSX  + (size_t)(bid * 2 + ih) * 256 + c] = xs;
    ws[OFF_PSXX + (size_t)(bid * 2 + ih) * 256 + c] = xs2;
    if (PCX) {
        float* pp = pcx + (size_t)((bid * 2 + ih) * 16) * 256 + c;
        #pragma unroll
        for (int k = 0; k < 16; ++k) pp[(size_t)k * 256] = acc[k];
    } else {
        #pragma unroll
        for (int k = 0; k < 16; ++k)
            atomicAdd(ws + OFF_CROSSR + ((0 * 4 + b) * 16 + k) * 256 + c, acc[k]);
        atomicAdd(ws + OFF_SXF + (size_t)(b * 8 + 0) * 256 + c, xs);
        atomicAdd(ws + OFF_SXF + (size_t)(b * 8 + 1) * 256 + c, xs2);
    }
}

// ---------------- Kernel 3: reduce Cross partials + Sx/Sxx finals ----------------
// grid 256 = 4(b) x 16(k) x 4(sg of 64 slab-halves); block 256 (t = c).
__global__ __launch_bounds__(256) void k_red(const float* __restrict__ pcx,
                                             float* __restrict__ ws) {
    int bid = blockIdx.x;
    int b  = bid >> 6;
    int k  = (bid >> 2) & 15;
    int sg = bid & 3;
    int c  = threadIdx.x;
    float acc = 0.f;
    #pragma unroll 8
    for (int j = 0; j < 64; ++j) {
        int r = sg * 64 + j;
        acc += pcx[(size_t)((b * 256 + r) * 16 + k) * 256 + c];
    }
    ws[OFF_CROSSR + ((sg * 4 + b) * 16 + k) * 256 + c] = acc;

    if (k == 0) {
        float sxq = 0.f;
        #pragma unroll 8
        for (int j = 0; j < 64; ++j)
            sxq += ws[OFF_PSX + (size_t)(b * 256 + sg * 64 + j) * 256 + c];
        ws[OFF_SXF + (size_t)((b * 4 + sg) * 2 + 0) * 256 + c] = sxq;
    } else if (k == 1) {
        float sxxq = 0.f;
        #pragma unroll 8
        for (int j = 0; j < 64; ++j)
            sxxq += ws[OFF_PSXX + (size_t)(b * 256 + sg * 64 + j) * 256 + c];
        ws[OFF_SXF + (size_t)((b * 4 + sg) * 2 + 1) * 256 + c] = sxxq;
    }
}

// ---------------- Kernel 4: final reductions + softmax + output ----------------
// grid 4 (b), block 256 (t = c). Derives SR/SRR/SCALE from psr partials.
__global__ __launch_bounds__(256) void k_final(const float* __restrict__ ws,
                                               float* __restrict__ out) {
    __shared__ float srl[4096];    // [s<128][32]
    __shared__ float fin[48];      // SR[16], SRR[16], SCALE[16]
    int b = blockIdx.x;
    int t = threadIdx.x;

    const float* psr = ws + OFF_PSR + (size_t)b * 128 * 32;
    #pragma unroll
    for (int j = 0; j < 16; ++j) srl[j * 256 + t] = psr[j * 256 + t];
    __syncthreads();

    if (t < 16) {
        float v = 0.f;
        for (int s = 0; s < 128; ++s) v += srl[s * 32 + t];
        fin[t] = v;                                   // SR[k2]
    } else if (t < 32) {
        int k = t - 16;
        float v = 0.f;
        for (int s = 0; s < 128; ++s) v += srl[s * 32 + 16 + k];
        fin[16 + k] = v;                              // SRR[k2]
    } else if (t < 48) {
        int kp = t - 32;
        float v = 0.f;
        for (int s = kp * 8; s < kp * 8 + 8; ++s)
            for (int k2 = 0; k2 < 16; ++k2) v += srl[s * 32 + k2];
        fin[32 + kp] = v;                             // SCALE[kp] (pre /4096)
    }
    __syncthreads();

    int c = t;
    float sx = 0.f, sxx = 0.f;
    #pragma unroll
    for (int sg = 0; sg < 4; ++sg) {
        sx  += ws[OFF_SXF + (size_t)((b * 4 + sg) * 2 + 0) * 256 + c];
        sxx += ws[OFF_SXF + (size_t)((b * 4 + sg) * 2 + 1) * 256 + c];
    }

    float sl2[16];
    float mx = -1e30f;
    #pragma unroll
    for (int k = 0; k < 16; ++k) {
        float cr = 0.f;
        #pragma unroll
        for (int sg = 0; sg < 4; ++sg)
            cr += ws[OFF_CROSSR + ((sg * 4 + b) * 16 + k) * 256 + c];
        float sc  = fin[32 + k] * (1.f / 4096.f);
        float srr = fin[16 + k];
        float v = sc * (sxx - 2.f * cr + srr);
        sl2[k] = v;
        mx = fmaxf(mx, v);
    }
    float den = 0.f;
    #pragma unroll
    for (int k = 0; k < 16; ++k) {
        float e = __expf(sl2[k] - mx);
        sl2[k] = e;
        den += e;
    }
    float inv = 1.f / den;
    #pragma unroll
    for (int k = 0; k < 16; ++k) {
        float srk = fin[k];
        out[(size_t)(b * 16 + k) * 256 + c] = sl2[k] * inv * (sx - srk);
    }
}

extern "C" void kernel_launch(void* const* d_in, const int* in_sizes, int n_in,
                              void* d_out, int out_size, void* d_ws, size_t ws_size,
                              hipStream_t stream) {
    const float* x     = (const float*)d_in[0];
    const float* w     = (const float*)d_in[1];
    const float* gamma = (const float*)d_in[2];
    const float* beta  = (const float*)d_in[3];
    float* ws  = (float*)d_ws;
    float* out = (float*)d_out;

    bool use_pcx = ws_size >= WS_NEED;   // constant across calls: graph-safe

    k_conv<<<256, 512, 0, stream>>>(x, w, ws + OFF_CW, ws + OFF_PBN);
    if (use_pcx) {
        k_main<true><<<512, 512, 0, stream>>>(x, gamma, beta, ws, ws + OFF_PCX);
        k_red<<<256, 256, 0, stream>>>(ws + OFF_PCX, ws);
    } else {
        hipMemsetAsync(ws + OFF_CROSSR, 0,
                       (OFF_CW - OFF_CROSSR) * sizeof(float), stream);
        k_main<false><<<512, 512, 0, stream>>>(x, gamma, beta, ws, nullptr);
    }
    k_final<<<4, 256, 0, stream>>>(ws, out);
}